// Round 4
// baseline (1280.227 us; speedup 1.0000x reference)
//
#include <hip/hip_runtime.h>
#include <stdint.h>

// Problem constants
#define DM   2048      // d_model
#define LSEQ 2048      // sequence length
#define NB   4         // batch
#define NH   16        // heads
#define HD   128       // head dim
#define BL   (NB*LSEQ) // 8192 rows

typedef unsigned short u16;
typedef short  short8 __attribute__((ext_vector_type(8)));   // 8 bf16 (4 VGPRs)
typedef float  f32x4  __attribute__((ext_vector_type(4)));

#define LOG2E 1.4426950408889634f

__device__ __forceinline__ float bf2f(u16 v) {
    union { unsigned u; float f; } x; x.u = ((unsigned)v) << 16; return x.f;
}
__device__ __forceinline__ u16 f2bf(float f) {
    union { float f; unsigned u; } x; x.f = f;
    return (u16)((x.u + 0x7FFF + ((x.u >> 16) & 1)) >> 16);   // RNE
}

// ---- dtype-adaptive input access -----------------------------------------
// Inputs may be fp32 (reference is float32) or bf16. Decided at runtime by
// dtype_probe; consumers read the count and branch uniformly.
__device__ __forceinline__ short8 ld8(const void* base, size_t e, bool f32) {
    if (f32) {
        const float* p = (const float*)base + e;
        f32x4 a = *(const f32x4*)p;
        f32x4 b = *(const f32x4*)(p + 4);
        short8 r;
        #pragma unroll
        for (int i = 0; i < 4; ++i) { r[i] = (short)f2bf(a[i]); r[4+i] = (short)f2bf(b[i]); }
        return r;
    }
    return *(const short8*)((const u16*)base + e);
}
__device__ __forceinline__ float lde(const void* b, size_t e, bool f32) {
    return f32 ? ((const float*)b)[e] : bf2f(((const u16*)b)[e]);
}
__device__ __forceinline__ void st1(void* b, size_t e, float v, bool f32) {
    if (f32) ((float*)b)[e] = v; else ((u16*)b)[e] = f2bf(v);
}

// Probe: count u16 words in x[0..4096) whose bf16-exponent is outside the
// plausible range for N(0,1) data. bf16 data -> ~0; fp32 data (low halves
// uniform bits) -> ~1600. Threshold 100.
extern "C" __global__ void dtype_probe(const u16* __restrict__ x, int* __restrict__ cnt) {
    int t = threadIdx.x;
    int insane = 0;
    #pragma unroll
    for (int j = 0; j < 16; ++j) {
        u16 u = x[t * 16 + j];
        int e = (u >> 7) & 0xFF;
        if (u != 0 && (e < 96 || e > 143)) insane++;
    }
    atomicAdd(cnt, insane);
}

// XOR swizzles: permute 8-element blocks within a row so strided b128
// accesses avoid power-of-2 bank aliasing.
__device__ __forceinline__ int swz128(int row, int col) {  // 128-col tiles
    return row*128 + ((((col >> 3) ^ row) & 15) << 3) + (col & 7);
}
__device__ __forceinline__ int swz64(int row, int col) {   // 64-col tiles
    return row*64 + ((((col >> 3) ^ row) & 7) << 3) + (col & 7);
}

// ---------------------------------------------------------------------------
// Diagnostics (kept one more round): zero non-finite bf16, set flag bit.
// ---------------------------------------------------------------------------
extern "C" __global__ void scan_fix(u16* __restrict__ buf, int n8,
                                    int* __restrict__ flags, int bit)
{
    int i = blockIdx.x * 256 + threadIdx.x;
    if (i >= n8) return;
    u16* p = buf + (size_t)i * 8;
    short8 v = *(const short8*)p;
    bool bad = false;
    #pragma unroll
    for (int j = 0; j < 8; ++j) {
        u16 u = (u16)v[j];
        if ((u & 0x7FFF) >= 0x7F80) { v[j] = 0; bad = true; }
    }
    if (bad) { *(short8*)p = v; atomicOr(flags, bit); }
}

// Sentinel: if any flag fired, overwrite out[0] with a decodable band.
// 100=q/k post-GEMM, 200=vT, 400=post-rmsrope, 800=flash, +2000 if fp32 path.
extern "C" __global__ void patch(const int* __restrict__ flags,
                                 const int* __restrict__ cnt, void* __restrict__ out)
{
    if (threadIdx.x == 0 && blockIdx.x == 0) {
        int f = *flags;
        bool isf = *cnt > 100;
        if (f) {
            float v = (isf ? 2000.f : 0.f)
                    + (f & 1 ? 100.f : 0.f) + (f & 2 ? 200.f : 0.f)
                    + (f & 4 ? 400.f : 0.f) + (f & 8 ? 800.f : 0.f);
            st1(out, 0, v, isf);
        }
    }
}

// ---------------------------------------------------------------------------
// GEMM core (register->LDS staging): C[m][n] = sum_k A[m][k]*W[n][k]
// BM=BN=128, BK=32, 256 threads (2x2 waves of 64x64), f32 accum.
// ---------------------------------------------------------------------------
__device__ __forceinline__ void gemm_core(const void* A, const void* W,
                                          u16* Al, u16* Bl,
                                          f32x4 acc[4][4],
                                          int m0, int n0, int t,
                                          bool af, bool wf)
{
    const int lane = t & 63, w = t >> 6;
    const int quad = lane >> 4, l15 = lane & 15;
    const int srow = t >> 2, scol = (t & 3) * 8;        // staging: 64B row-chunks
    const size_t abase = (size_t)(m0 + srow) * DM + scol;
    const size_t wbase = (size_t)(n0 + srow) * DM + scol;
    const int wm = (w >> 1) * 64, wn = (w & 1) * 64;

    for (int k0 = 0; k0 < DM; k0 += 32) {
        short8 a0 = ld8(A, abase + k0,                   af);
        short8 a1 = ld8(A, abase + k0 + (size_t)64 * DM, af);
        short8 b0 = ld8(W, wbase + k0,                   wf);
        short8 b1 = ld8(W, wbase + k0 + (size_t)64 * DM, wf);
        __syncthreads();                    // prior-iteration LDS reads done
        *(short8*)&Al[srow*32 + scol]      = a0;
        *(short8*)&Al[(64+srow)*32 + scol] = a1;
        *(short8*)&Bl[srow*32 + scol]      = b0;
        *(short8*)&Bl[(64+srow)*32 + scol] = b1;
        __syncthreads();
        short8 afr[4], bfr[4];
        #pragma unroll
        for (int mt = 0; mt < 4; ++mt)
            afr[mt] = *(const short8*)&Al[(wm + mt*16 + l15)*32 + quad*8];
        #pragma unroll
        for (int nt = 0; nt < 4; ++nt)
            bfr[nt] = *(const short8*)&Bl[(wn + nt*16 + l15)*32 + quad*8];
        #pragma unroll
        for (int mt = 0; mt < 4; ++mt)
            #pragma unroll
            for (int nt = 0; nt < 4; ++nt)
                acc[mt][nt] = __builtin_amdgcn_mfma_f32_16x16x32_bf16(
                                  afr[mt], bfr[nt], acc[mt][nt], 0, 0, 0);
    }
}

// GEMM, row-major output. a_sel/o_sel: 1 = that side follows input dtype,
// 0 = always bf16 (workspace). W always follows input dtype.
extern "C" __global__ void gemm_qk(const void* A, const void* W0, const void* W1,
                                   void* O0, void* O1, const int* cnt,
                                   int a_sel, int o_sel)
{
    __shared__ __align__(16) u16 Al[128*32];
    __shared__ __align__(16) u16 Bl[128*32];
    const bool isf = *cnt > 100;
    const bool af = a_sel && isf, wf = isf, of = o_sel && isf;
    const void* W = blockIdx.z ? W1 : W0;
    void*       O = blockIdx.z ? O1 : O0;
    const int n0 = blockIdx.x * 128, m0 = blockIdx.y * 128;
    const int t = threadIdx.x, lane = t & 63, w = t >> 6;
    const int quad = lane >> 4, l15 = lane & 15;
    const int wm = (w >> 1) * 64, wn = (w & 1) * 64;

    f32x4 acc[4][4];
    #pragma unroll
    for (int i = 0; i < 4; ++i)
        #pragma unroll
        for (int j = 0; j < 4; ++j) acc[i][j] = (f32x4){0.f, 0.f, 0.f, 0.f};

    gemm_core(A, W, Al, Bl, acc, m0, n0, t, af, wf);

    // C/D layout: col = lane&15, row = quad*4 + reg (m89/m91-verified)
    #pragma unroll
    for (int mt = 0; mt < 4; ++mt)
        #pragma unroll
        for (int r = 0; r < 4; ++r) {
            size_t base = (size_t)(m0 + wm + mt*16 + quad*4 + r) * DM + n0 + wn + l15;
            #pragma unroll
            for (int nt = 0; nt < 4; ++nt) st1(O, base + nt*16, acc[mt][nt][r], of);
        }
}

// V projection with TRANSPOSED bf16 output: vT[b][n=h*128+d][l].
extern "C" __global__ void gemm_v(const void* A, const void* W,
                                  u16* __restrict__ vT, const int* cnt)
{
    __shared__ __align__(16) u16 Al[128*32];
    __shared__ __align__(16) u16 Bl[128*32];
    __shared__ __align__(16) u16 Tl[128*128];
    const bool isf = *cnt > 100;
    const int n0 = blockIdx.x * 128, m0 = blockIdx.y * 128;
    const int t = threadIdx.x, lane = t & 63, w = t >> 6;
    const int quad = lane >> 4, l15 = lane & 15;
    const int wm = (w >> 1) * 64, wn = (w & 1) * 64;

    f32x4 acc[4][4];
    #pragma unroll
    for (int i = 0; i < 4; ++i)
        #pragma unroll
        for (int j = 0; j < 4; ++j) acc[i][j] = (f32x4){0.f, 0.f, 0.f, 0.f};

    gemm_core(A, W, Al, Bl, acc, m0, n0, t, isf, isf);

    #pragma unroll
    for (int mt = 0; mt < 4; ++mt)
        #pragma unroll
        for (int nt = 0; nt < 4; ++nt)
            #pragma unroll
            for (int r = 0; r < 4; ++r) {
                int m = wm + mt*16 + quad*4 + r;
                int n = wn + nt*16 + l15;
                Tl[swz128(n, m)] = f2bf(acc[mt][nt][r]);
            }
    __syncthreads();
    const int b  = m0 >> 11;           // 2048 rows per batch; tiles never straddle
    const int l0 = m0 & (LSEQ - 1);
    #pragma unroll
    for (int it = 0; it < 8; ++it) {
        int c = t + 256*it;
        int nr = c >> 4, m8 = (c & 15) * 8;
        short8 val = *(const short8*)&Tl[swz128(nr, m8)];
        *(short8*)(vT + (size_t)b*DM*LSEQ + (size_t)(n0 + nr)*LSEQ + l0 + m8) = val;
    }
}

// ---------------------------------------------------------------------------
// RMSNorm(128) + RoPE on q and k (bf16, in place). One wave per (b,l,h).
// cos/sin/gamma are inputs -> dtype-aware loads.
// ---------------------------------------------------------------------------
extern "C" __global__ void rmsrope(u16* __restrict__ q, u16* __restrict__ kk,
    const void* cq, const void* sq, const void* ck, const void* sk,
    const void* qg, const void* kg, const int* cnt)
{
    const bool isf = *cnt > 100;
    int t = blockIdx.x * 256 + threadIdx.x;
    int lane = t & 63;
    int widx = t >> 6;                 // (b*L + l)*16 + h
    int h  = widx & (NH - 1);
    int bl = widx >> 4;
    size_t ro = (size_t)bl * DM + (size_t)h * HD;
    size_t co = (size_t)bl * HD;

    {
        float e0 = bf2f(q[ro + lane]), e1 = bf2f(q[ro + lane + 64]);
        float ss = e0*e0 + e1*e1;
        #pragma unroll
        for (int sm = 1; sm < 64; sm <<= 1) ss += __shfl_xor(ss, sm, 64);
        float r = rsqrtf(ss * (1.f / HD) + 1e-6f);
        float y0 = e0 * r * lde(qg, lane, isf);
        float y1 = e1 * r * lde(qg, lane + 64, isf);
        float c0 = lde(cq, co + lane, isf), c1 = lde(cq, co + lane + 64, isf);
        float s0 = lde(sq, co + lane, isf), s1 = lde(sq, co + lane + 64, isf);
        q[ro + lane]      = f2bf(y0 * c0 - y1 * s0);
        q[ro + lane + 64] = f2bf(y1 * c1 + y0 * s1);
    }
    {
        float e0 = bf2f(kk[ro + lane]), e1 = bf2f(kk[ro + lane + 64]);
        float ss = e0*e0 + e1*e1;
        #pragma unroll
        for (int sm = 1; sm < 64; sm <<= 1) ss += __shfl_xor(ss, sm, 64);
        float r = rsqrtf(ss * (1.f / HD) + 1e-6f);
        float y0 = e0 * r * lde(kg, lane, isf);
        float y1 = e1 * r * lde(kg, lane + 64, isf);
        float c0 = lde(ck, co + lane, isf), c1 = lde(ck, co + lane + 64, isf);
        float s0 = lde(sk, co + lane, isf), s1 = lde(sk, co + lane + 64, isf);
        kk[ro + lane]      = f2bf(y0 * c0 - y1 * s0);
        kk[ro + lane + 64] = f2bf(y1 * c1 + y0 * s1);
    }
}

// ---------------------------------------------------------------------------
// Flash attention (non-causal, online softmax). All operands bf16 workspace.
// ---------------------------------------------------------------------------
extern "C" __global__ __launch_bounds__(256, 2) void flash(
    const u16* __restrict__ q, const u16* __restrict__ k,
    const u16* __restrict__ vT, u16* __restrict__ o)
{
    __shared__ __align__(16) u16 lds[24576];   // 48 KB
    u16* Kl = lds;          // 64x128
    u16* Vl = lds + 8192;   // 128x64 (V^T)
    u16* Pl = lds + 16384;  // 4 waves x 32x64

    const int bh = blockIdx.x, b = bh >> 4, h = bh & 15;
    const int q0 = blockIdx.y * 128;
    const int t = threadIdx.x, lane = t & 63, w = t >> 6;
    const int quad = lane >> 4, l15 = lane & 15;
    const size_t qko = (size_t)b * LSEQ * DM + (size_t)h * HD;          // q/k/o base
    const size_t vo  = (size_t)b * DM * LSEQ + (size_t)h * HD * LSEQ;   // vT base

    // Q fragments straight from global: A[m=l15][k=quad*8+j] per 16x16 tile
    short8 qf[2][4];
    #pragma unroll
    for (int mt = 0; mt < 2; ++mt)
        #pragma unroll
        for (int ks = 0; ks < 4; ++ks)
            qf[mt][ks] = *(const short8*)(q + qko +
                         (size_t)(q0 + w*32 + mt*16 + l15) * DM + ks*32 + quad*8);

    f32x4 acc[2][8];
    #pragma unroll
    for (int mt = 0; mt < 2; ++mt)
        #pragma unroll
        for (int dt = 0; dt < 8; ++dt) acc[mt][dt] = (f32x4){0.f, 0.f, 0.f, 0.f};
    float m2[2][4], ls[2][4];
    #pragma unroll
    for (int mt = 0; mt < 2; ++mt)
        #pragma unroll
        for (int r = 0; r < 4; ++r) { m2[mt][r] = -30000.f; ls[mt][r] = 0.f; }
    const float sl = 0.08838834764831845f * LOG2E;  // (1/sqrt(128))*log2(e)

    for (int kv0 = 0; kv0 < LSEQ; kv0 += 64) {
        __syncthreads();   // prior-iter Kl/Vl reads complete before restaging
        #pragma unroll
        for (int it = 0; it < 4; ++it) {           // K tile 64x128
            int c = t + 256*it;
            int row = c >> 4, c8 = (c & 15) * 8;
            short8 val = *(const short8*)(k + qko + (size_t)(kv0 + row) * DM + c8);
            *(short8*)&Kl[swz128(row, c8)] = val;
        }
        #pragma unroll
        for (int it = 0; it < 4; ++it) {           // V^T tile 128x64
            int c = t + 256*it;
            int d = c >> 3, c8 = (c & 7) * 8;
            short8 val = *(const short8*)(vT + vo + (size_t)d * LSEQ + kv0 + c8);
            *(short8*)&Vl[swz64(d, c8)] = val;
        }
        __syncthreads();

        f32x4 S[2][4];
        #pragma unroll
        for (int mt = 0; mt < 2; ++mt)
            #pragma unroll
            for (int nt = 0; nt < 4; ++nt) S[mt][nt] = (f32x4){0.f, 0.f, 0.f, 0.f};
        #pragma unroll
        for (int ks = 0; ks < 4; ++ks) {
            #pragma unroll
            for (int nt = 0; nt < 4; ++nt) {
                short8 bk = *(const short8*)&Kl[swz128(nt*16 + l15, ks*32 + quad*8)];
                S[0][nt] = __builtin_amdgcn_mfma_f32_16x16x32_bf16(qf[0][ks], bk, S[0][nt], 0,0,0);
                S[1][nt] = __builtin_amdgcn_mfma_f32_16x16x32_bf16(qf[1][ks], bk, S[1][nt], 0,0,0);
            }
        }

        #pragma unroll
        for (int mt = 0; mt < 2; ++mt) {
            float mc[4], rs[4];
            #pragma unroll
            for (int r = 0; r < 4; ++r)
                mc[r] = fmaxf(fmaxf(S[mt][0][r], S[mt][1][r]),
                              fmaxf(S[mt][2][r], S[mt][3][r]));
            #pragma unroll
            for (int sm = 1; sm < 16; sm <<= 1)
                #pragma unroll
                for (int r = 0; r < 4; ++r) mc[r] = fmaxf(mc[r], __shfl_xor(mc[r], sm, 64));
            #pragma unroll
            for (int r = 0; r < 4; ++r) {
                float mn = fmaxf(m2[mt][r], mc[r] * sl);     // log2-domain running max
                float al = exp2f(m2[mt][r] - mn);
                m2[mt][r] = mn;
                rs[r] = 0.f;
                #pragma unroll
                for (int nt = 0; nt < 4; ++nt) {
                    float p = exp2f(S[mt][nt][r] * sl - mn);
                    S[mt][nt][r] = p;
                    rs[r] += p;
                }
                ls[mt][r] *= al;
                #pragma unroll
                for (int dt = 0; dt < 8; ++dt) acc[mt][dt][r] *= al;
            }
            #pragma unroll
            for (int sm = 1; sm < 16; sm <<= 1)
                #pragma unroll
                for (int r = 0; r < 4; ++r) rs[r] += __shfl_xor(rs[r], sm, 64);
            #pragma unroll
            for (int r = 0; r < 4; ++r) ls[mt][r] += rs[r];
            #pragma unroll
            for (int nt = 0; nt < 4; ++nt)
                #pragma unroll
                for (int r = 0; r < 4; ++r)
                    Pl[w*2048 + swz64(mt*16 + quad*4 + r, nt*16 + l15)] = f2bf(S[mt][nt][r]);
        }

        #pragma unroll
        for (int ks2 = 0; ks2 < 2; ++ks2) {
            short8 ap0 = *(const short8*)&Pl[w*2048 + swz64(l15,      ks2*32 + quad*8)];
            short8 ap1 = *(const short8*)&Pl[w*2048 + swz64(16 + l15, ks2*32 + quad*8)];
            #pragma unroll
            for (int dt = 0; dt < 8; ++dt) {
                short8 bv = *(const short8*)&Vl[swz64(dt*16 + l15, ks2*32 + quad*8)];
                acc[0][dt] = __builtin_amdgcn_mfma_f32_16x16x32_bf16(ap0, bv, acc[0][dt], 0,0,0);
                acc[1][dt] = __builtin_amdgcn_mfma_f32_16x16x32_bf16(ap1, bv, acc[1][dt], 0,0,0);
            }
        }
    }

    #pragma unroll
    for (int mt = 0; mt < 2; ++mt)
        #pragma unroll
        for (int r = 0; r < 4; ++r) {
            float inv = 1.f / ls[mt][r];
            u16* op = o + qko + (size_t)(q0 + w*32 + mt*16 + quad*4 + r) * DM + l15;
            #pragma unroll
            for (int dt = 0; dt < 8; ++dt) op[dt*16] = f2bf(acc[mt][dt][r] * inv);
        }
}

// ---------------------------------------------------------------------------
extern "C" void kernel_launch(void* const* d_in, const int* in_sizes, int n_in,
                              void* d_out, int out_size, void* d_ws, size_t ws_size,
                              hipStream_t stream)
{
    const void* x  = d_in[0];
    const void* cq = d_in[1];
    const void* sq = d_in[2];
    const void* ck = d_in[3];
    const void* sk = d_in[4];
    const void* Wq = d_in[5];
    const void* Wk = d_in[6];
    const void* Wv = d_in[7];
    const void* Wo = d_in[8];
    const void* qg = d_in[9];
    const void* kg = d_in[10];

    // workspace: q, k, vT, attn_out (bf16) — 4 x 32 MiB = 128 MiB (+ flags/cnt)
    u16* qws = (u16*)d_ws;
    u16* kws = qws + (size_t)BL * DM;
    u16* vtw = kws + (size_t)BL * DM;
    u16* ows = vtw + (size_t)BL * DM;
    int* flg = (int*)(ows + (size_t)BL * DM);   // flg[0]=flags, flg[1]=dtype count
    int* cnt = flg + 1;

    const int n8 = BL * DM / 8;               // 2,097,152 8-elem chunks
    const int sg = (n8 + 255) / 256;          // scan grid

    hipMemsetAsync(flg, 0, 8, stream);
    dtype_probe<<<1, 256, 0, stream>>>((const u16*)x, cnt);

    gemm_qk<<<dim3(16, 64, 2), 256, 0, stream>>>(x, Wq, Wk, qws, kws, cnt, 1, 0);
    scan_fix<<<sg, 256, 0, stream>>>(qws, n8, flg, 1);
    scan_fix<<<sg, 256, 0, stream>>>(kws, n8, flg, 1);

    gemm_v <<<dim3(16, 64, 1), 256, 0, stream>>>(x, Wv, vtw, cnt);
    scan_fix<<<sg, 256, 0, stream>>>(vtw, n8, flg, 2);

    rmsrope<<<dim3(BL * NH / 4), 256, 0, stream>>>(qws, kws, cq, sq, ck, sk, qg, kg, cnt);
    scan_fix<<<sg, 256, 0, stream>>>(qws, n8, flg, 4);
    scan_fix<<<sg, 256, 0, stream>>>(kws, n8, flg, 4);

    flash  <<<dim3(64, 16), 256, 0, stream>>>(qws, kws, vtw, ows);
    scan_fix<<<sg, 256, 0, stream>>>(ows, n8, flg, 8);

    gemm_qk<<<dim3(16, 64, 1), 256, 0, stream>>>(ows, Wo, Wo, d_out, d_out, cnt, 0, 1);
    patch  <<<1, 64, 0, stream>>>(flg, cnt, d_out);
}